// Round 10
// baseline (419.231 us; speedup 1.0000x reference)
//
#include <hip/hip_runtime.h>
#include <hip/hip_bf16.h>
#include <math.h>

#define BDIM 4
#define TDIM 2048
#define CDIM 2048
#define HDIM 16
#define DDIM 128
#define MROWS (BDIM*TDIM)     /* 8192 */
#define NQKV (3*CDIM)         /* 6144 */
#define GK   CDIM             /* 2048 = K of both GEMMs */
#define QSZ  (MROWS*CDIM)

#define NTILES 32             /* GK/64 */
#define NITER  16             /* NTILES/2 */
#define HT     8192           /* bf16 units per [256][32] half-tile */
#define BOFF   32768          /* B region offset in bf16 units (4*HT) */

/* 1/sqrt(128) * log2(e): folded into W_qkv's Q rows at cvt time */
#define QSCALE 0.1275171f

typedef __attribute__((ext_vector_type(8))) short short8;
typedef __attribute__((ext_vector_type(4))) unsigned short ushort4v;
typedef __attribute__((ext_vector_type(4))) float f32x4;

__device__ __forceinline__ unsigned short f2bf(float f) {
    unsigned int u = __float_as_uint(f);
    u += 0x7fffu + ((u >> 16) & 1u);        // RNE
    return (unsigned short)(u >> 16);
}

__device__ __forceinline__ void gload16(const unsigned short* g, unsigned short* l) {
    __builtin_amdgcn_global_load_lds((__attribute__((address_space(1))) void*)(g),
                                     (__attribute__((address_space(3))) void*)(l),
                                     16, 0, 0);
}

// fused fp32 -> bf16 conversions for x, W_qkv (Q rows pre-scaled), W_out
__global__ __launch_bounds__(256) void cvt_all(const float* __restrict__ x,
                                               const float* __restrict__ wqkv,
                                               const float* __restrict__ wout,
                                               unsigned short* __restrict__ xb,
                                               unsigned short* __restrict__ wqkvb,
                                               unsigned short* __restrict__ woutb)
{
    const int stride = gridDim.x * blockDim.x;
    const int t0 = blockIdx.x * blockDim.x + threadIdx.x;
    for (int i = t0; i < MROWS*CDIM/4; i += stride) {
        float4 f = ((const float4*)x)[i];
        ushort4v u;
        u[0]=f2bf(f.x); u[1]=f2bf(f.y); u[2]=f2bf(f.z); u[3]=f2bf(f.w);
        ((ushort4v*)xb)[i] = u;
    }
    for (int i = t0; i < NQKV*CDIM/4; i += stride) {
        float4 f = ((const float4*)wqkv)[i];
        const float s = (i < CDIM*CDIM/4) ? QSCALE : 1.0f;   // scale W_q rows
        ushort4v u;
        u[0]=f2bf(f.x*s); u[1]=f2bf(f.y*s); u[2]=f2bf(f.z*s); u[3]=f2bf(f.w*s);
        ((ushort4v*)wqkvb)[i] = u;
    }
    for (int i = t0; i < CDIM*CDIM/4; i += stride) {
        float4 f = ((const float4*)wout)[i];
        ushort4v u;
        u[0]=f2bf(f.x); u[1]=f2bf(f.y); u[2]=f2bf(f.z); u[3]=f2bf(f.w);
        ((ushort4v*)woutb)[i] = u;
    }
}

// ---- 8-phase 256x256 bf16 NT GEMM (K-loop byte-identical since round 6) --
__device__ __forceinline__ void stage_half(const unsigned short* __restrict__ T,
                                           int rowbase, int kcol,
                                           unsigned short* dst, int w, int lane)
{
    const int sw = ((lane & 3) ^ ((lane >> 3) & 3)) * 8;
#pragma unroll
    for (int j = 0; j < 2; ++j) {
        const int r = w*32 + j*16 + (lane >> 2);
        gload16(T + (size_t)(rowbase + r)*GK + kcol + sw, dst + (w*32 + j*16)*32);
    }
}

template<int MQ, int KS, int BUF, bool RDB, bool WAIT>
__device__ __forceinline__ void gphase(unsigned short* lds,
    const unsigned short* __restrict__ stT, int stRow, int stKcol, unsigned short* stDst,
    int wr, int wc, int fr, int colu, int w, int lane,
    short8 (&bfr)[4], f32x4 (&acc)[8][4])
{
    const unsigned short* Ah = lds + (BUF*2 + KS)*HT;
    const unsigned short* Bh = lds + BOFF + (BUF*2 + KS)*HT;
    short8 af[4];
#pragma unroll
    for (int mi = 0; mi < 4; ++mi)
        af[mi] = *(const short8*)&Ah[(wr*128 + (MQ*4 + mi)*16 + fr)*32 + colu];
    if (RDB) {
#pragma unroll
        for (int nj = 0; nj < 4; ++nj)
            bfr[nj] = *(const short8*)&Bh[(wc*64 + nj*16 + fr)*32 + colu];
    }
    stage_half(stT, stRow, stKcol, stDst, w, lane);
    if (WAIT) asm volatile("s_waitcnt vmcnt(4)" ::: "memory");
    __builtin_amdgcn_s_barrier();
    asm volatile("s_waitcnt lgkmcnt(0)" ::: "memory");
    __builtin_amdgcn_sched_barrier(0);
    __builtin_amdgcn_s_setprio(1);
#pragma unroll
    for (int mi = 0; mi < 4; ++mi)
#pragma unroll
        for (int nj = 0; nj < 4; ++nj)
            acc[MQ*4 + mi][nj] = __builtin_amdgcn_mfma_f32_16x16x32_bf16(af[mi], bfr[nj], acc[MQ*4 + mi][nj], 0, 0, 0);
    __builtin_amdgcn_s_setprio(0);
    __builtin_amdgcn_s_barrier();
}

// MODE 0: scatter bf16 to Q/K [bh,t,d] and V TRANSPOSED [bh,d,t].
// MODE 1: fp32 row-major outp.
// RX: XCDs along M; each XCD gets a compact (gx/RX) x (gy*RX/8) tile region.
template<int MODE, int RX>
__global__ __launch_bounds__(512, 2) void gemm8(const unsigned short* __restrict__ A,
                                                const unsigned short* __restrict__ B,
                                                float* __restrict__ outp,
                                                unsigned short* __restrict__ qb,
                                                unsigned short* __restrict__ kb,
                                                unsigned short* __restrict__ vt,
                                                int Nsz)
{
    extern __shared__ unsigned short lds[];   // 8*HT bf16 = 128 KB
    const int tid  = threadIdx.x;
    const int w    = tid >> 6;
    const int lane = tid & 63;
    const int wr   = w >> 2, wc = w & 3;
    const int fr   = lane & 15;
    const int fg   = lane >> 4;
    const int colu = (fg ^ ((fr >> 1) & 3)) * 8;

    // T1: XCD-region swizzle (bijective; id%8 tracks HW XCD round-robin)
    const int gx  = gridDim.x, gy = gridDim.y;
    const int id  = blockIdx.x + blockIdx.y * gx;
    const int xcd = id & 7;
    const int jj  = id >> 3;
    const int mx  = gx / RX;
    const int my  = (gy * RX) >> 3;
    const int bx  = (xcd % RX) * mx + (jj % mx);
    const int by  = (xcd / RX) * my + (jj / mx);
    const int m0  = bx * 256, n0 = by * 256;

    f32x4 acc[8][4];
#pragma unroll
    for (int i = 0; i < 8; ++i)
#pragma unroll
        for (int j = 0; j < 4; ++j) acc[i][j] = (f32x4)(0.f);
    short8 bfr[4];

    stage_half(A, m0, 0,  lds,             w, lane);
    stage_half(B, n0, 0,  lds + BOFF,      w, lane);
    stage_half(A, m0, 32, lds + HT,        w, lane);
    stage_half(B, n0, 32, lds + BOFF + HT, w, lane);
    stage_half(A, m0, 64, lds + 2*HT,        w, lane);
    stage_half(B, n0, 64, lds + BOFF + 2*HT, w, lane);
    asm volatile("s_waitcnt vmcnt(0)" ::: "memory");
    __builtin_amdgcn_s_barrier();

    for (int i = 0; i < NITER; ++i) {
        const int t1 = 2*i + 1;
        const int t2 = (2*i + 2 < NTILES) ? 2*i + 2 : 0;
        const int t3 = (2*i + 3 < NTILES) ? 2*i + 3 : 0;
        gphase<0,0,0,true ,false>(lds, A, m0, t1*64+32, lds + 3*HT,        wr, wc, fr, colu, w, lane, bfr, acc);
        gphase<1,0,0,false,false>(lds, B, n0, t1*64+32, lds + BOFF + 3*HT, wr, wc, fr, colu, w, lane, bfr, acc);
        gphase<0,1,0,true ,false>(lds, A, m0, t2*64,    lds,               wr, wc, fr, colu, w, lane, bfr, acc);
        gphase<1,1,0,false,true >(lds, B, n0, t2*64,    lds + BOFF,        wr, wc, fr, colu, w, lane, bfr, acc);
        gphase<0,0,1,true ,false>(lds, A, m0, t2*64+32, lds + HT,          wr, wc, fr, colu, w, lane, bfr, acc);
        gphase<1,0,1,false,false>(lds, B, n0, t2*64+32, lds + BOFF + HT,   wr, wc, fr, colu, w, lane, bfr, acc);
        gphase<0,1,1,true ,false>(lds, A, m0, t3*64,    lds + 2*HT,        wr, wc, fr, colu, w, lane, bfr, acc);
        gphase<1,1,1,false,true >(lds, B, n0, t3*64,    lds + BOFF + 2*HT, wr, wc, fr, colu, w, lane, bfr, acc);
    }
    asm volatile("s_waitcnt vmcnt(0)" ::: "memory");

    if (MODE == 0) {
#pragma unroll
        for (int mi = 0; mi < 8; ++mi)
#pragma unroll
            for (int nj = 0; nj < 4; ++nj) {
                const int n   = n0 + wc*64 + nj*16 + fr;
                const int sel = n >> 11;
                const int c   = n & 2047;
                const int hh  = c >> 7, dd = c & 127;
                const int mb  = m0 + wr*128 + mi*16 + fg*4;
                const int bb  = mb >> 11, tt = mb & 2047;
                if (sel == 2) {
                    ushort4v v;
#pragma unroll
                    for (int r = 0; r < 4; ++r) v[r] = f2bf(acc[mi][nj][r]);
                    *(ushort4v*)&vt[((size_t)(bb*HDIM + hh)*DDIM + dd)*TDIM + tt] = v;
                } else {
                    unsigned short* dstb = (sel == 0) ? qb : kb;
#pragma unroll
                    for (int r = 0; r < 4; ++r)
                        dstb[((size_t)(bb*HDIM + hh)*TDIM + tt + r)*DDIM + dd] = f2bf(acc[mi][nj][r]);
                }
            }
    } else {
#pragma unroll
        for (int mi = 0; mi < 8; ++mi)
#pragma unroll
            for (int nj = 0; nj < 4; ++nj) {
                const int n = n0 + wc*64 + nj*16 + fr;
#pragma unroll
                for (int r = 0; r < 4; ++r) {
                    const int m = m0 + wr*128 + mi*16 + fg*4 + r;
                    outp[(size_t)m*Nsz + n] = acc[mi][nj][r];
                }
            }
    }
}

// ---- Flash attention (byte-identical to round-9 version) ------------------
__global__ __launch_bounds__(512) void attn_mfma(const unsigned short* __restrict__ Qg,
                                                 const unsigned short* __restrict__ Kg,
                                                 const unsigned short* __restrict__ Vt,
                                                 unsigned short* __restrict__ attb)
{
    extern __shared__ unsigned short smem[];
    unsigned short* KsB = smem;            // 2 x 8192 shorts
    unsigned short* VsB = smem + 16384;    // 2 x 8192 shorts
    unsigned short* Ps  = smem + 32768;    // 8192 shorts

    const int tid  = threadIdx.x;
    const int w    = tid >> 6;             // 0..7
    const int lane = tid & 63;
    const int g    = lane >> 4;
    const int c    = lane & 15;
    const int bh   = blockIdx.x & 63;
    const int qb_  = 15 - (blockIdx.x >> 6);   // heavy blocks first
    const int q0   = qb_ * 128;
    const int qt   = 2*qb_ + 1;                // last K-tile index
    const int qw   = q0 + w*16;                // wave's first q row

    const unsigned short* Kbh  = Kg + (size_t)bh*TDIM*DDIM;
    const unsigned short* Vtbh = Vt + (size_t)bh*DDIM*TDIM;

    short8 qf[4];
    {
        const unsigned short* qrow = Qg + ((size_t)bh*TDIM + qw + c)*DDIM + g*8;
#pragma unroll
        for (int s = 0; s < 4; ++s)
            qf[s] = *(const short8*)(qrow + s*32);
    }

    short8 onesf;
#pragma unroll
    for (int j = 0; j < 8; ++j) onesf[j] = (short)0x3F80;   // 1.0 bf16

    f32x4 oacc[8];
#pragma unroll
    for (int i = 0; i < 8; ++i) oacc[i] = (f32x4)(0.f);
    float m_r[4], l_r[4];
#pragma unroll
    for (int r = 0; r < 4; ++r) { m_r[r] = -INFINITY; l_r[r] = 0.f; }

#define STAGE_K(buf, kt_)                                                        \
    {                                                                            \
        _Pragma("unroll")                                                        \
        for (int j = 0; j < 2; ++j) {                                            \
            const int rw  = (w<<3) + (j<<2) + (lane >> 4);                       \
            const int sub = (lane & 15) ^ (rw & 7);                              \
            gload16(Kbh + ((size_t)((kt_)*64 + rw))*DDIM + sub*8,                \
                    &KsB[(buf)*8192 + ((w<<3) + (j<<2))*128]);                   \
        }                                                                        \
    }
#define STAGE_V(buf, kt_)                                                        \
    {                                                                            \
        _Pragma("unroll")                                                        \
        for (int j = 0; j < 2; ++j) {                                            \
            const int d   = (w<<4) + (j<<3) + (lane >> 3);                       \
            const int sub = (lane & 7) ^ (d & 7);                                \
            gload16(Vtbh + (size_t)d*TDIM + (kt_)*64 + sub*8,                    \
                    &VsB[(buf)*8192 + ((w<<4) + (j<<3))*64]);                    \
        }                                                                        \
    }

    STAGE_K(0, 0);
    STAGE_V(0, 0);
    __syncthreads();

    for (int kt = 0; kt <= qt; ++kt) {
        const int cur = kt & 1;
        if (kt < qt) { STAGE_K(cur ^ 1, kt + 1); STAGE_V(cur ^ 1, kt + 1); }

        const bool active = (kt*64) <= (qw + 15);   // wave-uniform

        if (active) {
            f32x4 sa[4];
#pragma unroll
            for (int n = 0; n < 4; ++n) sa[n] = (f32x4)(0.f);
#pragma unroll
            for (int s = 0; s < 4; ++s)
#pragma unroll
                for (int n = 0; n < 4; ++n) {
                    const int row = n*16 + c;
                    short8 bf = *(const short8*)&KsB[cur*8192 + ((row*128 + s*32 + g*8) ^ ((row&7)<<3))];
                    sa[n] = __builtin_amdgcn_mfma_f32_16x16x32_bf16(qf[s], bf, sa[n], 0, 0, 0);
                }

            if (kt*64 + 63 > qw) {
#pragma unroll
                for (int n = 0; n < 4; ++n) {
                    const int kgl = kt*64 + n*16 + c;
#pragma unroll
                    for (int r = 0; r < 4; ++r) {
                        const int qgl = qw + g*4 + r;
                        if (kgl > qgl) sa[n][r] = -INFINITY;
                    }
                }
            }

            f32x4 p[4];
            bool slow = (kt == 0);
            if (!slow) {
#pragma unroll
                for (int n = 0; n < 4; ++n)
#pragma unroll
                    for (int r = 0; r < 4; ++r)
                        p[n][r] = exp2f(sa[n][r] - m_r[r]);
                float pm = p[0][0];
#pragma unroll
                for (int n = 0; n < 4; ++n)
#pragma unroll
                    for (int r = 0; r < 4; ++r)
                        pm = fmaxf(pm, p[n][r]);
                slow = __any(pm > 256.0f);    // P bounded by 2^8
            }
            if (slow) {
                float corr[4];
#pragma unroll
                for (int r = 0; r < 4; ++r) {
                    float mx = fmaxf(fmaxf(sa[0][r], sa[1][r]), fmaxf(sa[2][r], sa[3][r]));
                    mx = fmaxf(mx, __shfl_xor(mx, 1));
                    mx = fmaxf(mx, __shfl_xor(mx, 2));
                    mx = fmaxf(mx, __shfl_xor(mx, 4));
                    mx = fmaxf(mx, __shfl_xor(mx, 8));
                    const float mn = fmaxf(m_r[r], mx);
                    corr[r] = exp2f(m_r[r] - mn);
                    m_r[r] = mn;
                }
#pragma unroll
                for (int n = 0; n < 4; ++n)
#pragma unroll
                    for (int r = 0; r < 4; ++r)
                        p[n][r] = exp2f(sa[n][r] - m_r[r]);
#pragma unroll
                for (int i = 0; i < 8; ++i) {
                    f32x4 o = oacc[i];
                    o[0] *= corr[0]; o[1] *= corr[1]; o[2] *= corr[2]; o[3] *= corr[3];
                    oacc[i] = o;
                }
#pragma unroll
                for (int r = 0; r < 4; ++r) l_r[r] *= corr[r];
            }

            unsigned short* Pw = &Ps[w*1024];
#pragma unroll
            for (int n = 0; n < 4; ++n)
#pragma unroll
                for (int r = 0; r < 4; ++r) {
                    const int q = g*4 + r, k = n*16 + c;
                    Pw[(q*64 + k) ^ ((q&7)<<3)] = f2bf(p[n][r]);
                }
            short8 pf[2];
#pragma unroll
            for (int s2 = 0; s2 < 2; ++s2)
                pf[s2] = *(const short8*)&Pw[(c*64 + s2*32 + g*8) ^ ((c&7)<<3)];

            f32x4 rs = (f32x4)(0.f);
            rs = __builtin_amdgcn_mfma_f32_16x16x32_bf16(pf[0], onesf, rs, 0, 0, 0);
            rs = __builtin_amdgcn_mfma_f32_16x16x32_bf16(pf[1], onesf, rs, 0, 0, 0);
#pragma unroll
            for (int r = 0; r < 4; ++r) l_r[r] += rs[r];

#pragma unroll
            for (int s2 = 0; s2 < 2; ++s2)
#pragma unroll
                for (int dt = 0; dt < 8; ++dt) {
                    const int d = dt*16 + c;
                    short8 vf = *(const short8*)&VsB[cur*8192 + ((d*64 + s2*32 + g*8) ^ ((d&7)<<3))];
                    oacc[dt] = __builtin_amdgcn_mfma_f32_16x16x32_bf16(pf[s2], vf, oacc[dt], 0, 0, 0);
                }
        }

        __syncthreads();   // drains vmcnt: next-tile K/V landed; all reads of cur done
    }

    float inv[4];
#pragma unroll
    for (int r = 0; r < 4; ++r) inv[r] = 1.f / l_r[r];
    const int b = bh >> 4, h = bh & 15;
    unsigned short* obase = attb + ((size_t)b*TDIM + qw + g*4)*CDIM + h*DDIM + c;
#pragma unroll
    for (int dt = 0; dt < 8; ++dt)
#pragma unroll
        for (int r = 0; r < 4; ++r)
            obase[(size_t)r*CDIM + dt*16] = f2bf(oacc[dt][r] * inv[r]);
}

extern "C" void kernel_launch(void* const* d_in, const int* in_sizes, int n_in,
                              void* d_out, int out_size, void* d_ws, size_t ws_size,
                              hipStream_t stream)
{
    const float* x    = (const float*)d_in[0];   // [B,T,C]
    const float* Wqkv = (const float*)d_in[1];   // [3C,C]
    const float* Wout = (const float*)d_in[2];   // [C,C]
    float* out = (float*)d_out;

    unsigned short* ws = (unsigned short*)d_ws;
    unsigned short* xb    = ws;
    unsigned short* Wqkvb = xb    + (size_t)MROWS*CDIM;
    unsigned short* Woutb = Wqkvb + (size_t)NQKV*CDIM;
    unsigned short* Qb    = Woutb + (size_t)CDIM*CDIM;    // [bh,t,d] (pre-scaled via W)
    unsigned short* Kb    = Qb + QSZ;                     // [bh,t,d]
    unsigned short* Vtb   = Kb + QSZ;                     // [bh,d,t]
    unsigned short* attb  = Vtb + QSZ;                    // [B,T,C]

    cvt_all<<<2048, 256, 0, stream>>>(x, Wqkv, Wout, xb, Wqkvb, Woutb);
    gemm8<0,4><<<dim3(MROWS/256, NQKV/256), 512, 131072, stream>>>(xb, Wqkvb, nullptr, Qb, Kb, Vtb, NQKV);
    attn_mfma<<<dim3(64*16), 512, 81920, stream>>>(Qb, Kb, Vtb, attb);
    gemm8<1,2><<<dim3(MROWS/256, CDIM/256), 512, 131072, stream>>>(attb, Woutb, out, nullptr, nullptr, nullptr, CDIM);
}

// Round 11
// 395.387 us; speedup vs baseline: 1.0603x; 1.0603x over previous
//
#include <hip/hip_runtime.h>
#include <hip/hip_bf16.h>
#include <math.h>

#define BDIM 4
#define TDIM 2048
#define CDIM 2048
#define HDIM 16
#define DDIM 128
#define MROWS (BDIM*TDIM)     /* 8192 */
#define NQKV (3*CDIM)         /* 6144 */
#define GK   CDIM             /* 2048 = K of both GEMMs */
#define QSZ  (MROWS*CDIM)

#define NTILES 32             /* GK/64 */
#define NITER  16             /* NTILES/2 */
#define HT     8192           /* bf16 units per [256][32] half-tile */
#define BOFF   32768          /* B region offset in bf16 units (4*HT) */

/* 1/sqrt(128) * log2(e): folded into W_qkv's Q rows at cvt time */
#define QSCALE 0.1275171f

typedef __attribute__((ext_vector_type(8))) short short8;
typedef __attribute__((ext_vector_type(4))) unsigned short ushort4v;
typedef __attribute__((ext_vector_type(4))) float f32x4;
typedef __attribute__((ext_vector_type(16))) float f32x16;

__device__ __forceinline__ unsigned short f2bf(float f) {
    unsigned int u = __float_as_uint(f);
    u += 0x7fffu + ((u >> 16) & 1u);        // RNE
    return (unsigned short)(u >> 16);
}

__device__ __forceinline__ unsigned int cvtpk_bf16(float lo, float hi) {
    unsigned int r;
    asm("v_cvt_pk_bf16_f32 %0, %1, %2" : "=v"(r) : "v"(lo), "v"(hi));
    return r;
}

__device__ __forceinline__ void gload16(const unsigned short* g, unsigned short* l) {
    __builtin_amdgcn_global_load_lds((__attribute__((address_space(1))) void*)(g),
                                     (__attribute__((address_space(3))) void*)(l),
                                     16, 0, 0);
}

// fused fp32 -> bf16 conversions for x, W_qkv (Q rows pre-scaled), W_out
__global__ __launch_bounds__(256) void cvt_all(const float* __restrict__ x,
                                               const float* __restrict__ wqkv,
                                               const float* __restrict__ wout,
                                               unsigned short* __restrict__ xb,
                                               unsigned short* __restrict__ wqkvb,
                                               unsigned short* __restrict__ woutb)
{
    const int stride = gridDim.x * blockDim.x;
    const int t0 = blockIdx.x * blockDim.x + threadIdx.x;
    for (int i = t0; i < MROWS*CDIM/4; i += stride) {
        float4 f = ((const float4*)x)[i];
        ushort4v u;
        u[0]=f2bf(f.x); u[1]=f2bf(f.y); u[2]=f2bf(f.z); u[3]=f2bf(f.w);
        ((ushort4v*)xb)[i] = u;
    }
    for (int i = t0; i < NQKV*CDIM/4; i += stride) {
        float4 f = ((const float4*)wqkv)[i];
        const float s = (i < CDIM*CDIM/4) ? QSCALE : 1.0f;   // scale W_q rows
        ushort4v u;
        u[0]=f2bf(f.x*s); u[1]=f2bf(f.y*s); u[2]=f2bf(f.z*s); u[3]=f2bf(f.w*s);
        ((ushort4v*)wqkvb)[i] = u;
    }
    for (int i = t0; i < CDIM*CDIM/4; i += stride) {
        float4 f = ((const float4*)wout)[i];
        ushort4v u;
        u[0]=f2bf(f.x); u[1]=f2bf(f.y); u[2]=f2bf(f.z); u[3]=f2bf(f.w);
        ((ushort4v*)woutb)[i] = u;
    }
}

// ---- 8-phase 256x256 bf16 NT GEMM (byte-identical to round-10) -----------
__device__ __forceinline__ void stage_half(const unsigned short* __restrict__ T,
                                           int rowbase, int kcol,
                                           unsigned short* dst, int w, int lane)
{
    const int sw = ((lane & 3) ^ ((lane >> 3) & 3)) * 8;
#pragma unroll
    for (int j = 0; j < 2; ++j) {
        const int r = w*32 + j*16 + (lane >> 2);
        gload16(T + (size_t)(rowbase + r)*GK + kcol + sw, dst + (w*32 + j*16)*32);
    }
}

template<int MQ, int KS, int BUF, bool RDB, bool WAIT>
__device__ __forceinline__ void gphase(unsigned short* lds,
    const unsigned short* __restrict__ stT, int stRow, int stKcol, unsigned short* stDst,
    int wr, int wc, int fr, int colu, int w, int lane,
    short8 (&bfr)[4], f32x4 (&acc)[8][4])
{
    const unsigned short* Ah = lds + (BUF*2 + KS)*HT;
    const unsigned short* Bh = lds + BOFF + (BUF*2 + KS)*HT;
    short8 af[4];
#pragma unroll
    for (int mi = 0; mi < 4; ++mi)
        af[mi] = *(const short8*)&Ah[(wr*128 + (MQ*4 + mi)*16 + fr)*32 + colu];
    if (RDB) {
#pragma unroll
        for (int nj = 0; nj < 4; ++nj)
            bfr[nj] = *(const short8*)&Bh[(wc*64 + nj*16 + fr)*32 + colu];
    }
    stage_half(stT, stRow, stKcol, stDst, w, lane);
    if (WAIT) asm volatile("s_waitcnt vmcnt(4)" ::: "memory");
    __builtin_amdgcn_s_barrier();
    asm volatile("s_waitcnt lgkmcnt(0)" ::: "memory");
    __builtin_amdgcn_sched_barrier(0);
    __builtin_amdgcn_s_setprio(1);
#pragma unroll
    for (int mi = 0; mi < 4; ++mi)
#pragma unroll
        for (int nj = 0; nj < 4; ++nj)
            acc[MQ*4 + mi][nj] = __builtin_amdgcn_mfma_f32_16x16x32_bf16(af[mi], bfr[nj], acc[MQ*4 + mi][nj], 0, 0, 0);
    __builtin_amdgcn_s_setprio(0);
    __builtin_amdgcn_s_barrier();
}

template<int MODE, int RX>
__global__ __launch_bounds__(512, 2) void gemm8(const unsigned short* __restrict__ A,
                                                const unsigned short* __restrict__ B,
                                                float* __restrict__ outp,
                                                unsigned short* __restrict__ qb,
                                                unsigned short* __restrict__ kb,
                                                unsigned short* __restrict__ vt,
                                                int Nsz)
{
    extern __shared__ unsigned short lds[];   // 8*HT bf16 = 128 KB
    const int tid  = threadIdx.x;
    const int w    = tid >> 6;
    const int lane = tid & 63;
    const int wr   = w >> 2, wc = w & 3;
    const int fr   = lane & 15;
    const int fg   = lane >> 4;
    const int colu = (fg ^ ((fr >> 1) & 3)) * 8;

    const int gx  = gridDim.x, gy = gridDim.y;
    const int id  = blockIdx.x + blockIdx.y * gx;
    const int xcd = id & 7;
    const int jj  = id >> 3;
    const int mx  = gx / RX;
    const int my  = (gy * RX) >> 3;
    const int bx  = (xcd % RX) * mx + (jj % mx);
    const int by  = (xcd / RX) * my + (jj / mx);
    const int m0  = bx * 256, n0 = by * 256;

    f32x4 acc[8][4];
#pragma unroll
    for (int i = 0; i < 8; ++i)
#pragma unroll
        for (int j = 0; j < 4; ++j) acc[i][j] = (f32x4)(0.f);
    short8 bfr[4];

    stage_half(A, m0, 0,  lds,             w, lane);
    stage_half(B, n0, 0,  lds + BOFF,      w, lane);
    stage_half(A, m0, 32, lds + HT,        w, lane);
    stage_half(B, n0, 32, lds + BOFF + HT, w, lane);
    stage_half(A, m0, 64, lds + 2*HT,        w, lane);
    stage_half(B, n0, 64, lds + BOFF + 2*HT, w, lane);
    asm volatile("s_waitcnt vmcnt(0)" ::: "memory");
    __builtin_amdgcn_s_barrier();

    for (int i = 0; i < NITER; ++i) {
        const int t1 = 2*i + 1;
        const int t2 = (2*i + 2 < NTILES) ? 2*i + 2 : 0;
        const int t3 = (2*i + 3 < NTILES) ? 2*i + 3 : 0;
        gphase<0,0,0,true ,false>(lds, A, m0, t1*64+32, lds + 3*HT,        wr, wc, fr, colu, w, lane, bfr, acc);
        gphase<1,0,0,false,false>(lds, B, n0, t1*64+32, lds + BOFF + 3*HT, wr, wc, fr, colu, w, lane, bfr, acc);
        gphase<0,1,0,true ,false>(lds, A, m0, t2*64,    lds,               wr, wc, fr, colu, w, lane, bfr, acc);
        gphase<1,1,0,false,true >(lds, B, n0, t2*64,    lds + BOFF,        wr, wc, fr, colu, w, lane, bfr, acc);
        gphase<0,0,1,true ,false>(lds, A, m0, t2*64+32, lds + HT,          wr, wc, fr, colu, w, lane, bfr, acc);
        gphase<1,0,1,false,false>(lds, B, n0, t2*64+32, lds + BOFF + HT,   wr, wc, fr, colu, w, lane, bfr, acc);
        gphase<0,1,1,true ,false>(lds, A, m0, t3*64,    lds + 2*HT,        wr, wc, fr, colu, w, lane, bfr, acc);
        gphase<1,1,1,false,true >(lds, B, n0, t3*64,    lds + BOFF + 2*HT, wr, wc, fr, colu, w, lane, bfr, acc);
    }
    asm volatile("s_waitcnt vmcnt(0)" ::: "memory");

    if (MODE == 0) {
#pragma unroll
        for (int mi = 0; mi < 8; ++mi)
#pragma unroll
            for (int nj = 0; nj < 4; ++nj) {
                const int n   = n0 + wc*64 + nj*16 + fr;
                const int sel = n >> 11;
                const int c   = n & 2047;
                const int hh  = c >> 7, dd = c & 127;
                const int mb  = m0 + wr*128 + mi*16 + fg*4;
                const int bb  = mb >> 11, tt = mb & 2047;
                if (sel == 2) {
                    ushort4v v;
#pragma unroll
                    for (int r = 0; r < 4; ++r) v[r] = f2bf(acc[mi][nj][r]);
                    *(ushort4v*)&vt[((size_t)(bb*HDIM + hh)*DDIM + dd)*TDIM + tt] = v;
                } else {
                    unsigned short* dstb = (sel == 0) ? qb : kb;
#pragma unroll
                    for (int r = 0; r < 4; ++r)
                        dstb[((size_t)(bb*HDIM + hh)*TDIM + tt + r)*DDIM + dd] = f2bf(acc[mi][nj][r]);
                }
            }
    } else {
#pragma unroll
        for (int mi = 0; mi < 8; ++mi)
#pragma unroll
            for (int nj = 0; nj < 4; ++nj) {
                const int n = n0 + wc*64 + nj*16 + fr;
#pragma unroll
                for (int r = 0; r < 4; ++r) {
                    const int m = m0 + wr*128 + mi*16 + fg*4 + r;
                    outp[(size_t)m*Nsz + n] = acc[mi][nj][r];
                }
            }
    }
}

// ---- Flash attention: swapped-QK^T 32x32, 8 waves x 32 q-rows = 256/block
// S^T = mfma32(K,Q): lane owns q-column (lanes l, l+32 share q). Softmax
// lane-local (1 shfl_xor(32)). P->PV A-frag via cvt_pk + shfl_xor exchange
// (no LDS round-trip). K/V double-buffered, KVBLK=64, defer-max.
__global__ __launch_bounds__(512) void attn_mfma(const unsigned short* __restrict__ Qg,
                                                 const unsigned short* __restrict__ Kg,
                                                 const unsigned short* __restrict__ Vt,
                                                 unsigned short* __restrict__ attb)
{
    extern __shared__ unsigned short smem[];
    unsigned short* KsB = smem;            // 2 x [64][128] (4-bit XOR swizzle)
    unsigned short* VsB = smem + 16384;    // 2 x [128][64] (3-bit XOR swizzle)

    const int tid  = threadIdx.x;
    const int w    = tid >> 6;             // 0..7
    const int lane = tid & 63;
    const int lq   = lane & 31;            // q-col (QK) / d-col (PV) / kv-row (K-frag)
    const int hi   = lane >> 5;            // k-group select
    const int bh   = blockIdx.x & 63;
    const int qb_  = 7 - (blockIdx.x >> 6);    // heavy blocks first
    const int q0   = qb_ * 256;
    const int qt   = 4*qb_ + 3;                // last 64-wide K-tile
    const int qw   = q0 + w*32;                // wave's first q row

    const unsigned short* Kbh  = Kg + (size_t)bh*TDIM*DDIM;
    const unsigned short* Vtbh = Vt + (size_t)bh*DDIM*TDIM;

    // Q fragments (B-operand of swapped QK): qf[ds] = Q[qw+lq][ds*16+hi*8+j]
    short8 qf[8];
    {
        const unsigned short* qrow = Qg + ((size_t)bh*TDIM + qw + lq)*DDIM + hi*8;
#pragma unroll
        for (int ds = 0; ds < 8; ++ds)
            qf[ds] = *(const short8*)(qrow + ds*16);
    }

    f32x16 oacc[4];
#pragma unroll
    for (int i = 0; i < 4; ++i) oacc[i] = (f32x16)(0.f);
    float m_r = -INFINITY, l_r = 0.f;

#define STAGE_K(buf, kt_)                                                        \
    {                                                                            \
        _Pragma("unroll")                                                        \
        for (int j = 0; j < 2; ++j) {                                            \
            const int rw  = (w<<3) + (j<<2) + (lane >> 4);                       \
            const int sub = (lane & 15) ^ (rw & 15);                             \
            gload16(Kbh + ((size_t)((kt_)*64 + rw))*DDIM + sub*8,                \
                    &KsB[(buf)*8192 + ((w<<3) + (j<<2))*128]);                   \
        }                                                                        \
    }
#define STAGE_V(buf, kt_)                                                        \
    {                                                                            \
        _Pragma("unroll")                                                        \
        for (int j = 0; j < 2; ++j) {                                            \
            const int d   = (w<<4) + (j<<3) + (lane >> 3);                       \
            const int sub = (lane & 7) ^ (d & 7);                                \
            gload16(Vtbh + (size_t)d*TDIM + (kt_)*64 + sub*8,                    \
                    &VsB[(buf)*8192 + ((w<<4) + (j<<3))*64]);                    \
        }                                                                        \
    }

    STAGE_K(0, 0);
    STAGE_V(0, 0);
    __syncthreads();

    for (int kt = 0; kt <= qt; ++kt) {
        const int cur = kt & 1;
        if (kt < qt) { STAGE_K(cur ^ 1, kt + 1); STAGE_V(cur ^ 1, kt + 1); }

#pragma unroll
        for (int ks2 = 0; ks2 < 2; ++ks2) {
            const int ktb = kt*64 + ks2*32;
            if (ktb <= qw + 31) {              // wave-uniform causal activity
                // S^T[kv32][q32]
                f32x16 sa = (f32x16)(0.f);
#pragma unroll
                for (int ds = 0; ds < 8; ++ds) {
                    const int kvl = ks2*32 + lq;
                    short8 kf = *(const short8*)&KsB[cur*8192 +
                        ((kvl*128 + ds*16 + hi*8) ^ ((kvl & 15) << 3))];
                    sa = __builtin_amdgcn_mfma_f32_32x32x16_bf16(kf, qf[ds], sa, 0, 0, 0);
                }

                if (ktb + 31 > qw) {           // diagonal overlap: causal mask
#pragma unroll
                    for (int r = 0; r < 16; ++r) {
                        const int kvg = ktb + (r&3) + 8*(r>>2) + 4*hi;
                        if (kvg > qw + lq) sa[r] = -INFINITY;
                    }
                }

                // defer-max softmax (scalar m,l per lane-pair)
                float p[16];
                bool slow = (kt == 0) && (ks2 == 0);
                if (!slow) {
                    float pm = 0.f;
#pragma unroll
                    for (int r = 0; r < 16; ++r) {
                        p[r] = exp2f(sa[r] - m_r);
                        pm = fmaxf(pm, p[r]);
                    }
                    slow = __any(pm > 256.0f);
                }
                if (slow) {
                    float mx = sa[0];
#pragma unroll
                    for (int r = 1; r < 16; ++r) mx = fmaxf(mx, sa[r]);
                    mx = fmaxf(mx, __shfl_xor(mx, 32));
                    const float mn = fmaxf(m_r, mx);
                    const float corr = exp2f(m_r - mn);
                    m_r = mn;
#pragma unroll
                    for (int r = 0; r < 16; ++r) p[r] = exp2f(sa[r] - m_r);
                    l_r *= corr;
#pragma unroll
                    for (int r = 0; r < 16; ++r) {
                        const float cr = __shfl(corr, (r&3) + 8*(r>>2) + 4*hi);
#pragma unroll
                        for (int dt = 0; dt < 4; ++dt) oacc[dt][r] *= cr;
                    }
                }

                float ls = 0.f;
#pragma unroll
                for (int r = 0; r < 16; ++r) ls += p[r];
                l_r += ls + __shfl_xor(ls, 32);

                // P -> PV A-frags: cvt_pk + shfl_xor(32) exchange
                short8 pa[2];
#pragma unroll
                for (int ks = 0; ks < 2; ++ks) {
                    const unsigned int wA = cvtpk_bf16(p[8*ks+0], p[8*ks+1]);
                    const unsigned int wB = cvtpk_bf16(p[8*ks+2], p[8*ks+3]);
                    const unsigned int wC = cvtpk_bf16(p[8*ks+4], p[8*ks+5]);
                    const unsigned int wD = cvtpk_bf16(p[8*ks+6], p[8*ks+7]);
                    const unsigned int u = __shfl_xor(hi ? wA : wC, 32);
                    const unsigned int v = __shfl_xor(hi ? wB : wD, 32);
                    unsigned int a0 = hi ? u  : wA;
                    unsigned int a1 = hi ? v  : wB;
                    unsigned int a2 = hi ? wC : u;
                    unsigned int a3 = hi ? wD : v;
                    unsigned int aw[4] = {a0, a1, a2, a3};
                    pa[ks] = *(short8*)aw;
                }

                // O += P V  (4 d-tiles of 32)
#pragma unroll
                for (int ks = 0; ks < 2; ++ks)
#pragma unroll
                    for (int dt = 0; dt < 4; ++dt) {
                        const int d = dt*32 + lq;
                        short8 vf = *(const short8*)&VsB[cur*8192 +
                            ((d*64 + ks2*32 + ks*16 + hi*8) ^ ((d & 7) << 3))];
                        oacc[dt] = __builtin_amdgcn_mfma_f32_32x32x16_bf16(pa[ks], vf, oacc[dt], 0, 0, 0);
                    }
            }
        }

        __syncthreads();   // drains vmcnt: next-tile K/V landed; reads of cur done
    }

    // epilogue: per-reg q-row, fetch inv(l) from owner lane, write bf16
    const float inv = 1.f / l_r;
    const int b = bh >> 4, h = bh & 15;
#pragma unroll
    for (int r = 0; r < 16; ++r) {
        const int qrw = (r&3) + 8*(r>>2) + 4*hi;
        const float invq = __shfl(inv, qrw);
        unsigned short* obase = attb + ((size_t)b*TDIM + qw + qrw)*CDIM + h*DDIM + lq;
#pragma unroll
        for (int dt = 0; dt < 4; ++dt)
            obase[dt*32] = f2bf(oacc[dt][r] * invq);
    }
}

extern "C" void kernel_launch(void* const* d_in, const int* in_sizes, int n_in,
                              void* d_out, int out_size, void* d_ws, size_t ws_size,
                              hipStream_t stream)
{
    const float* x    = (const float*)d_in[0];   // [B,T,C]
    const float* Wqkv = (const float*)d_in[1];   // [3C,C]
    const float* Wout = (const float*)d_in[2];   // [C,C]
    float* out = (float*)d_out;

    unsigned short* ws = (unsigned short*)d_ws;
    unsigned short* xb    = ws;
    unsigned short* Wqkvb = xb    + (size_t)MROWS*CDIM;
    unsigned short* Woutb = Wqkvb + (size_t)NQKV*CDIM;
    unsigned short* Qb    = Woutb + (size_t)CDIM*CDIM;    // [bh,t,d] (pre-scaled via W)
    unsigned short* Kb    = Qb + QSZ;                     // [bh,t,d]
    unsigned short* Vtb   = Kb + QSZ;                     // [bh,d,t]
    unsigned short* attb  = Vtb + QSZ;                    // [B,T,C]

    cvt_all<<<2048, 256, 0, stream>>>(x, Wqkv, Wout, xb, Wqkvb, Woutb);
    gemm8<0,4><<<dim3(MROWS/256, NQKV/256), 512, 131072, stream>>>(xb, Wqkvb, nullptr, Qb, Kb, Vtb, NQKV);
    attn_mfma<<<dim3(64*8), 512, 65536, stream>>>(Qb, Kb, Vtb, attb);
    gemm8<1,2><<<dim3(MROWS/256, CDIM/256), 512, 131072, stream>>>(attb, Woutb, out, nullptr, nullptr, nullptr, CDIM);
}

// Round 13
// 394.955 us; speedup vs baseline: 1.0615x; 1.0011x over previous
//
#include <hip/hip_runtime.h>
#include <hip/hip_bf16.h>
#include <math.h>

#define BDIM 4
#define TDIM 2048
#define CDIM 2048
#define HDIM 16
#define DDIM 128
#define MROWS (BDIM*TDIM)     /* 8192 */
#define NQKV (3*CDIM)         /* 6144 */
#define GK   CDIM             /* 2048 = K of both GEMMs */
#define QSZ  (MROWS*CDIM)

#define NTILES 32             /* GK/64 */
#define NITER  16             /* NTILES/2 */
#define HT     8192           /* bf16 units per [256][32] half-tile */
#define BOFF   32768          /* B region offset in bf16 units (4*HT) */

/* 1/sqrt(128) * log2(e): folded into W_qkv's Q rows at cvt time */
#define QSCALE 0.1275171f

typedef __attribute__((ext_vector_type(8))) short short8;
typedef __attribute__((ext_vector_type(4))) unsigned short ushort4v;
typedef __attribute__((ext_vector_type(4))) float f32x4;
typedef __attribute__((ext_vector_type(16))) float f32x16;

__device__ __forceinline__ unsigned short f2bf(float f) {
    unsigned int u = __float_as_uint(f);
    u += 0x7fffu + ((u >> 16) & 1u);        // RNE
    return (unsigned short)(u >> 16);
}

__device__ __forceinline__ unsigned int cvtpk_bf16(float lo, float hi) {
    unsigned int r;
    asm("v_cvt_pk_bf16_f32 %0, %1, %2" : "=v"(r) : "v"(lo), "v"(hi));
    return r;
}

__device__ __forceinline__ void gload16(const unsigned short* g, unsigned short* l) {
    __builtin_amdgcn_global_load_lds((__attribute__((address_space(1))) void*)(g),
                                     (__attribute__((address_space(3))) void*)(l),
                                     16, 0, 0);
}

// fused fp32 -> bf16 conversions for x, W_qkv (Q rows pre-scaled), W_out
__global__ __launch_bounds__(256) void cvt_all(const float* __restrict__ x,
                                               const float* __restrict__ wqkv,
                                               const float* __restrict__ wout,
                                               unsigned short* __restrict__ xb,
                                               unsigned short* __restrict__ wqkvb,
                                               unsigned short* __restrict__ woutb)
{
    const int stride = gridDim.x * blockDim.x;
    const int t0 = blockIdx.x * blockDim.x + threadIdx.x;
    for (int i = t0; i < MROWS*CDIM/4; i += stride) {
        float4 f = ((const float4*)x)[i];
        ushort4v u;
        u[0]=f2bf(f.x); u[1]=f2bf(f.y); u[2]=f2bf(f.z); u[3]=f2bf(f.w);
        ((ushort4v*)xb)[i] = u;
    }
    for (int i = t0; i < NQKV*CDIM/4; i += stride) {
        float4 f = ((const float4*)wqkv)[i];
        const float s = (i < CDIM*CDIM/4) ? QSCALE : 1.0f;   // scale W_q rows
        ushort4v u;
        u[0]=f2bf(f.x*s); u[1]=f2bf(f.y*s); u[2]=f2bf(f.z*s); u[3]=f2bf(f.w*s);
        ((ushort4v*)wqkvb)[i] = u;
    }
    for (int i = t0; i < CDIM*CDIM/4; i += stride) {
        float4 f = ((const float4*)wout)[i];
        ushort4v u;
        u[0]=f2bf(f.x); u[1]=f2bf(f.y); u[2]=f2bf(f.z); u[3]=f2bf(f.w);
        ((ushort4v*)woutb)[i] = u;
    }
}

// ---- 8-phase 256x256 bf16 NT GEMM ----------------------------------------
// Region map (bf16 units): A0=0, A1=HT, A2=2HT, A3=3HT (+BOFF for B).
// Stage->read ledger (uniform lag-6 phases):
//   P1/P2 stage A3,B3<-t1  read P7/P8 same iter
//   P3/P4 stage A0,B0<-t2  read P1/P2 next iter
//   P5/P6 stage A1,B1<-t2  read P3/P4 next iter
//   P7/P8 stage A2,B2<-t3  read P5/P6 next iter
// Waits: vmcnt(8) at EVERY even phase = newest 4 phases' stages (8 loads) may
// be in flight; each lag-6 read is covered by the wait one phase earlier.
// (Round-11's vmcnt(4)@P4/P8 over-tightened: forced stages home in ~2.5
// phases -> L3-latency stall. This plan is pointwise weaker = fewer stalls.)
__device__ __forceinline__ void stage_half(const unsigned short* __restrict__ T,
                                           int rowbase, int kcol,
                                           unsigned short* dst, int w, int lane)
{
    const int sw = ((lane & 3) ^ ((lane >> 3) & 3)) * 8;
#pragma unroll
    for (int j = 0; j < 2; ++j) {
        const int r = w*32 + j*16 + (lane >> 2);
        gload16(T + (size_t)(rowbase + r)*GK + kcol + sw, dst + (w*32 + j*16)*32);
    }
}

template<int MQ, int KS, int BUF, bool RDB, int WN>
__device__ __forceinline__ void gphase(unsigned short* lds,
    const unsigned short* __restrict__ stT, int stRow, int stKcol, unsigned short* stDst,
    int wr, int wc, int fr, int colu, int w, int lane,
    short8 (&bfr)[4], f32x4 (&acc)[8][4])
{
    const unsigned short* Ah = lds + (BUF*2 + KS)*HT;
    const unsigned short* Bh = lds + BOFF + (BUF*2 + KS)*HT;
    short8 af[4];
#pragma unroll
    for (int mi = 0; mi < 4; ++mi)
        af[mi] = *(const short8*)&Ah[(wr*128 + (MQ*4 + mi)*16 + fr)*32 + colu];
    if (RDB) {
#pragma unroll
        for (int nj = 0; nj < 4; ++nj)
            bfr[nj] = *(const short8*)&Bh[(wc*64 + nj*16 + fr)*32 + colu];
    }
    stage_half(stT, stRow, stKcol, stDst, w, lane);
    if (WN == 8) asm volatile("s_waitcnt vmcnt(8)" ::: "memory");
    __builtin_amdgcn_s_barrier();
    asm volatile("s_waitcnt lgkmcnt(0)" ::: "memory");
    __builtin_amdgcn_sched_barrier(0);
    __builtin_amdgcn_s_setprio(1);
#pragma unroll
    for (int mi = 0; mi < 4; ++mi)
#pragma unroll
        for (int nj = 0; nj < 4; ++nj)
            acc[MQ*4 + mi][nj] = __builtin_amdgcn_mfma_f32_16x16x32_bf16(af[mi], bfr[nj], acc[MQ*4 + mi][nj], 0, 0, 0);
    __builtin_amdgcn_s_setprio(0);
    __builtin_amdgcn_s_barrier();
}

template<int MODE, int RX>
__global__ __launch_bounds__(512, 2) void gemm8(const unsigned short* __restrict__ A,
                                                const unsigned short* __restrict__ B,
                                                float* __restrict__ outp,
                                                unsigned short* __restrict__ qb,
                                                unsigned short* __restrict__ kb,
                                                unsigned short* __restrict__ vt,
                                                int Nsz)
{
    extern __shared__ unsigned short lds[];   // 8*HT bf16 = 128 KB
    const int tid  = threadIdx.x;
    const int w    = tid >> 6;
    const int lane = tid & 63;
    const int wr   = w >> 2, wc = w & 3;
    const int fr   = lane & 15;
    const int fg   = lane >> 4;
    const int colu = (fg ^ ((fr >> 1) & 3)) * 8;

    const int gx  = gridDim.x, gy = gridDim.y;
    const int id  = blockIdx.x + blockIdx.y * gx;
    const int xcd = id & 7;
    const int jj  = id >> 3;
    const int mx  = gx / RX;
    const int my  = (gy * RX) >> 3;
    const int bx  = (xcd % RX) * mx + (jj % mx);
    const int by  = (xcd / RX) * my + (jj / mx);
    const int m0  = bx * 256, n0 = by * 256;

    f32x4 acc[8][4];
#pragma unroll
    for (int i = 0; i < 8; ++i)
#pragma unroll
        for (int j = 0; j < 4; ++j) acc[i][j] = (f32x4)(0.f);
    short8 bfr[4];

    stage_half(A, m0, 0,  lds,             w, lane);   // A0 <- t0 lo
    stage_half(B, n0, 0,  lds + BOFF,      w, lane);   // B0 <- t0 lo
    stage_half(A, m0, 32, lds + HT,        w, lane);   // A1 <- t0 hi
    stage_half(B, n0, 32, lds + BOFF + HT, w, lane);   // B1 <- t0 hi
    stage_half(A, m0, 64, lds + 2*HT,        w, lane); // A2 <- t1 lo
    stage_half(B, n0, 64, lds + BOFF + 2*HT, w, lane); // B2 <- t1 lo
    asm volatile("s_waitcnt vmcnt(0)" ::: "memory");
    __builtin_amdgcn_s_barrier();

    for (int i = 0; i < NITER; ++i) {
        const int t1 = 2*i + 1;
        const int t2 = (2*i + 2 < NTILES) ? 2*i + 2 : 0;
        const int t3 = (2*i + 3 < NTILES) ? 2*i + 3 : 0;
        gphase<0,0,0,true ,0>(lds, A, m0, t1*64+32, lds + 3*HT,        wr, wc, fr, colu, w, lane, bfr, acc); // P1
        gphase<1,0,0,false,8>(lds, B, n0, t1*64+32, lds + BOFF + 3*HT, wr, wc, fr, colu, w, lane, bfr, acc); // P2
        gphase<0,1,0,true ,0>(lds, A, m0, t2*64,    lds,               wr, wc, fr, colu, w, lane, bfr, acc); // P3
        gphase<1,1,0,false,8>(lds, B, n0, t2*64,    lds + BOFF,        wr, wc, fr, colu, w, lane, bfr, acc); // P4
        gphase<0,0,1,true ,0>(lds, A, m0, t2*64+32, lds + HT,          wr, wc, fr, colu, w, lane, bfr, acc); // P5
        gphase<1,0,1,false,8>(lds, B, n0, t2*64+32, lds + BOFF + HT,   wr, wc, fr, colu, w, lane, bfr, acc); // P6
        gphase<0,1,1,true ,0>(lds, A, m0, t3*64,    lds + 2*HT,        wr, wc, fr, colu, w, lane, bfr, acc); // P7
        gphase<1,1,1,false,8>(lds, B, n0, t3*64,    lds + BOFF + 2*HT, wr, wc, fr, colu, w, lane, bfr, acc); // P8
    }
    asm volatile("s_waitcnt vmcnt(0)" ::: "memory");

    if (MODE == 0) {
#pragma unroll
        for (int mi = 0; mi < 8; ++mi)
#pragma unroll
            for (int nj = 0; nj < 4; ++nj) {
                const int n   = n0 + wc*64 + nj*16 + fr;
                const int sel = n >> 11;
                const int c   = n & 2047;
                const int hh  = c >> 7, dd = c & 127;
                const int mb  = m0 + wr*128 + mi*16 + fg*4;
                const int bb  = mb >> 11, tt = mb & 2047;
                if (sel == 2) {
                    ushort4v v;
#pragma unroll
                    for (int r = 0; r < 4; ++r) v[r] = f2bf(acc[mi][nj][r]);
                    *(ushort4v*)&vt[((size_t)(bb*HDIM + hh)*DDIM + dd)*TDIM + tt] = v;
                } else {
                    unsigned short* dstb = (sel == 0) ? qb : kb;
#pragma unroll
                    for (int r = 0; r < 4; ++r)
                        dstb[((size_t)(bb*HDIM + hh)*TDIM + tt + r)*DDIM + dd] = f2bf(acc[mi][nj][r]);
                }
            }
    } else {
#pragma unroll
        for (int mi = 0; mi < 8; ++mi)
#pragma unroll
            for (int nj = 0; nj < 4; ++nj) {
                const int n = n0 + wc*64 + nj*16 + fr;
#pragma unroll
                for (int r = 0; r < 4; ++r) {
                    const int m = m0 + wr*128 + mi*16 + fg*4 + r;
                    outp[(size_t)m*Nsz + n] = acc[mi][nj][r];
                }
            }
    }
}

// ---- Flash attention (byte-identical to round-11 version) -----------------
__global__ __launch_bounds__(512) void attn_mfma(const unsigned short* __restrict__ Qg,
                                                 const unsigned short* __restrict__ Kg,
                                                 const unsigned short* __restrict__ Vt,
                                                 unsigned short* __restrict__ attb)
{
    extern __shared__ unsigned short smem[];
    unsigned short* KsB = smem;            // 2 x [64][128] (4-bit XOR swizzle)
    unsigned short* VsB = smem + 16384;    // 2 x [128][64] (3-bit XOR swizzle)

    const int tid  = threadIdx.x;
    const int w    = tid >> 6;             // 0..7
    const int lane = tid & 63;
    const int lq   = lane & 31;            // q-col (QK) / d-col (PV) / kv-row (K-frag)
    const int hi   = lane >> 5;            // k-group select
    const int bh   = blockIdx.x & 63;
    const int qb_  = 7 - (blockIdx.x >> 6);    // heavy blocks first
    const int q0   = qb_ * 256;
    const int qt   = 4*qb_ + 3;                // last 64-wide K-tile
    const int qw   = q0 + w*32;                // wave's first q row

    const unsigned short* Kbh  = Kg + (size_t)bh*TDIM*DDIM;
    const unsigned short* Vtbh = Vt + (size_t)bh*DDIM*TDIM;

    short8 qf[8];
    {
        const unsigned short* qrow = Qg + ((size_t)bh*TDIM + qw + lq)*DDIM + hi*8;
#pragma unroll
        for (int ds = 0; ds < 8; ++ds)
            qf[ds] = *(const short8*)(qrow + ds*16);
    }

    f32x16 oacc[4];
#pragma unroll
    for (int i = 0; i < 4; ++i) oacc[i] = (f32x16)(0.f);
    float m_r = -INFINITY, l_r = 0.f;

#define STAGE_K(buf, kt_)                                                        \
    {                                                                            \
        _Pragma("unroll")                                                        \
        for (int j = 0; j < 2; ++j) {                                            \
            const int rw  = (w<<3) + (j<<2) + (lane >> 4);                       \
            const int sub = (lane & 15) ^ (rw & 15);                             \
            gload16(Kbh + ((size_t)((kt_)*64 + rw))*DDIM + sub*8,                \
                    &KsB[(buf)*8192 + ((w<<3) + (j<<2))*128]);                   \
        }                                                                        \
    }
#define STAGE_V(buf, kt_)                                                        \
    {                                                                            \
        _Pragma("unroll")                                                        \
        for (int j = 0; j < 2; ++j) {                                            \
            const int d   = (w<<4) + (j<<3) + (lane >> 3);                       \
            const int sub = (lane & 7) ^ (d & 7);                                \
            gload16(Vtbh + (size_t)d*TDIM + (kt_)*64 + sub*8,                    \
                    &VsB[(buf)*8192 + ((w<<4) + (j<<3))*64]);                    \
        }                                                                        \
    }

    STAGE_K(0, 0);
    STAGE_V(0, 0);
    __syncthreads();

    for (int kt = 0; kt <= qt; ++kt) {
        const int cur = kt & 1;
        if (kt < qt) { STAGE_K(cur ^ 1, kt + 1); STAGE_V(cur ^ 1, kt + 1); }

#pragma unroll
        for (int ks2 = 0; ks2 < 2; ++ks2) {
            const int ktb = kt*64 + ks2*32;
            if (ktb <= qw + 31) {              // wave-uniform causal activity
                f32x16 sa = (f32x16)(0.f);
#pragma unroll
                for (int ds = 0; ds < 8; ++ds) {
                    const int kvl = ks2*32 + lq;
                    short8 kf = *(const short8*)&KsB[cur*8192 +
                        ((kvl*128 + ds*16 + hi*8) ^ ((kvl & 15) << 3))];
                    sa = __builtin_amdgcn_mfma_f32_32x32x16_bf16(kf, qf[ds], sa, 0, 0, 0);
                }

                if (ktb + 31 > qw) {
#pragma unroll
                    for (int r = 0; r < 16; ++r) {
                        const int kvg = ktb + (r&3) + 8*(r>>2) + 4*hi;
                        if (kvg > qw + lq) sa[r] = -INFINITY;
                    }
                }

                float p[16];
                bool slow = (kt == 0) && (ks2 == 0);
                if (!slow) {
                    float pm = 0.f;
#pragma unroll
                    for (int r = 0; r < 16; ++r) {
                        p[r] = exp2f(sa[r] - m_r);
                        pm = fmaxf(pm, p[r]);
                    }
                    slow = __any(pm > 256.0f);
                }
                if (slow) {
                    float mx = sa[0];
#pragma unroll
                    for (int r = 1; r < 16; ++r) mx = fmaxf(mx, sa[r]);
                    mx = fmaxf(mx, __shfl_xor(mx, 32));
                    const float mn = fmaxf(m_r, mx);
                    const float corr = exp2f(m_r - mn);
                    m_r = mn;
#pragma unroll
                    for (int r = 0; r < 16; ++r) p[r] = exp2f(sa[r] - m_r);
                    l_r *= corr;
#pragma unroll
                    for (int r = 0; r < 16; ++r) {
                        const float cr = __shfl(corr, (r&3) + 8*(r>>2) + 4*hi);
#pragma unroll
                        for (int dt = 0; dt < 4; ++dt) oacc[dt][r] *= cr;
                    }
                }

                float ls = 0.f;
#pragma unroll
                for (int r = 0; r < 16; ++r) ls += p[r];
                l_r += ls + __shfl_xor(ls, 32);

                short8 pa[2];
#pragma unroll
                for (int ks = 0; ks < 2; ++ks) {
                    const unsigned int wA = cvtpk_bf16(p[8*ks+0], p[8*ks+1]);
                    const unsigned int wB = cvtpk_bf16(p[8*ks+2], p[8*ks+3]);
                    const unsigned int wC = cvtpk_bf16(p[8*ks+4], p[8*ks+5]);
                    const unsigned int wD = cvtpk_bf16(p[8*ks+6], p[8*ks+7]);
                    const unsigned int u = __shfl_xor(hi ? wA : wC, 32);
                    const unsigned int v = __shfl_xor(hi ? wB : wD, 32);
                    unsigned int a0 = hi ? u  : wA;
                    unsigned int a1 = hi ? v  : wB;
                    unsigned int a2 = hi ? wC : u;
                    unsigned int a3 = hi ? wD : v;
                    unsigned int aw[4] = {a0, a1, a2, a3};
                    pa[ks] = *(short8*)aw;
                }

#pragma unroll
                for (int ks = 0; ks < 2; ++ks)
#pragma unroll
                    for (int dt = 0; dt < 4; ++dt) {
                        const int d = dt*32 + lq;
                        short8 vf = *(const short8*)&VsB[cur*8192 +
                            ((d*64 + ks2*32 + ks*16 + hi*8) ^ ((d & 7) << 3))];
                        oacc[dt] = __builtin_amdgcn_mfma_f32_32x32x16_bf16(pa[ks], vf, oacc[dt], 0, 0, 0);
                    }
            }
        }

        __syncthreads();
    }

    const float inv = 1.f / l_r;
    const int b = bh >> 4, h = bh & 15;
#pragma unroll
    for (int r = 0; r < 16; ++r) {
        const int qrw = (r&3) + 8*(r>>2) + 4*hi;
        const float invq = __shfl(inv, qrw);
        unsigned short* obase = attb + ((size_t)b*TDIM + qw + qrw)*CDIM + h*DDIM + lq;
#pragma unroll
        for (int dt = 0; dt < 4; ++dt)
            obase[dt*32] = f2bf(oacc[dt][r] * invq);
    }
}

extern "C" void kernel_launch(void* const* d_in, const int* in_sizes, int n_in,
                              void* d_out, int out_size, void* d_ws, size_t ws_size,
                              hipStream_t stream)
{
    const float* x    = (const float*)d_in[0];   // [B,T,C]
    const float* Wqkv = (const float*)d_in[1];   // [3C,C]
    const float* Wout = (const float*)d_in[2];   // [C,C]
    float* out = (float*)d_out;

    unsigned short* ws = (unsigned short*)d_ws;
    unsigned short* xb    = ws;
    unsigned short* Wqkvb = xb    + (size_t)MROWS*CDIM;
    unsigned short* Woutb = Wqkvb + (size_t)NQKV*CDIM;
    unsigned short* Qb    = Woutb + (size_t)CDIM*CDIM;    // [bh,t,d] (pre-scaled via W)
    unsigned short* Kb    = Qb + QSZ;                     // [bh,t,d]
    unsigned short* Vtb   = Kb + QSZ;                     // [bh,d,t]
    unsigned short* attb  = Vtb + QSZ;                    // [B,T,C]

    cvt_all<<<2048, 256, 0, stream>>>(x, Wqkv, Wout, xb, Wqkvb, Woutb);
    gemm8<0,4><<<dim3(MROWS/256, NQKV/256), 512, 131072, stream>>>(xb, Wqkvb, nullptr, Qb, Kb, Vtb, NQKV);
    attn_mfma<<<dim3(64*8), 512, 65536, stream>>>(Qb, Kb, Vtb, attb);
    gemm8<1,2><<<dim3(MROWS/256, CDIM/256), 512, 131072, stream>>>(attb, Woutb, out, nullptr, nullptr, nullptr, CDIM);
}